// Round 5
// baseline (15.455 us; speedup 1.0000x reference)
//
#include <hip/hip_runtime.h>

// out[b,f,o,r] = log( sum_cin softmax(logits)[o,cin,ki,kj,r] * exp(ll[b,f,cin,r]) )
// ki=(f>>5)&3, kj=f&3. B=128, F=1024, CIN=16, COUT=16, K=4, R=2.
//
// v6: kk-uniform waves, zero E-staging. Each block owns ONE kk slice
// (f = 128c + 32ki + 4d + kj); its 4KB softmax-weight table in LDS is read
// as pure 64-lane BROADCAST float4s (conflict-free by definition). Each
// row's 32 inputs live in VGPRs via 8 direct global float4 loads (lane owns
// its 128B line; L1 absorbs the per-instr spread). Two paired lanes share a
// row (h = output half): duplicate loads merge in the coalescer, stores
// tile each 128B output line exactly. Single phase, one barrier (lgkmcnt
// only - global loads stay in flight across it), 16 waves/CU.

__global__ __launch_bounds__(256, 4) void sumconv_fused(
    const float* __restrict__ ll, const float* __restrict__ logits,
    float* __restrict__ out) {
  __shared__ float wlds[1024];  // [p][ci][oo][r] : p*64 + ci*4 + oo*2 + r

  const int tid = threadIdx.x;
  const int blk = blockIdx.x;
  const int kk = blk >> 6;          // 16 kk values x 64 blocks each
  const int s  = blk & 63;
  const int ki = kk >> 2, kj = kk & 3;

  // thread -> (row, half). Paired lanes (2t, 2t+1) share one row.
  const int rp = s * 128 + (tid >> 1);  // [0, 8192) rows of this kk
  const int bb = rp >> 6;               // batch 0..127
  const int cd = rp & 63;
  const int f  = 128 * (cd >> 3) + 32 * ki + 4 * (cd & 7) + kj;
  const int h  = tid & 1;               // output half: p in [4h, 4h+4)

  // ---- issue the row's 8 global loads first (stay in flight past barrier) ----
  const float4* __restrict__ src = (const float4*)(ll + ((size_t)bb * 1024 + f) * 32);
  float4 L[8];
#pragma unroll
  for (int j = 0; j < 8; ++j) L[j] = src[j];

  // ---- softmax of this block's single kk slice: 32 tasks (o,r) ----
  if (tid < 32) {
    const int o = tid >> 1, r = tid & 1;
    // logits float index: o*512 + ci*32 + ki*8 + kj*2 + r  (kk*2 == ki*8+kj*2)
    const float* __restrict__ lg = logits + o * 512 + kk * 2 + r;
    float v[16];
    float m = -1e30f;
#pragma unroll
    for (int ci = 0; ci < 16; ++ci) {
      v[ci] = lg[ci * 32];
      m = fmaxf(m, v[ci]);
    }
    float sum = 0.f;
#pragma unroll
    for (int ci = 0; ci < 16; ++ci) {
      v[ci] = __expf(v[ci] - m);
      sum += v[ci];
    }
    const float inv = 1.0f / sum;
#pragma unroll
    for (int ci = 0; ci < 16; ++ci)
      wlds[(o >> 1) * 64 + ci * 4 + (o & 1) * 2 + r] = v[ci] * inv;
  }
  asm volatile("s_waitcnt lgkmcnt(0)" ::: "memory");
  __builtin_amdgcn_s_barrier();

  // ---- exp of own row (implicit vmcnt wait lands here, after the barrier) ----
  float E[32];
#pragma unroll
  for (int j = 0; j < 8; ++j) {
    E[4 * j + 0] = __expf(L[j].x);
    E[4 * j + 1] = __expf(L[j].y);
    E[4 * j + 2] = __expf(L[j].z);
    E[4 * j + 3] = __expf(L[j].w);
  }

  // ---- 4 o-pairs: broadcast W float4 per (p,ci), 16 independent FMA chains ----
  float4* __restrict__ op = (float4*)(out + ((size_t)bb * 1024 + f) * 32);
#pragma unroll
  for (int pp = 0; pp < 4; ++pp) {
    const float* __restrict__ wp = wlds + (4 * h + pp) * 64;
    float a00 = 0.f, a01 = 0.f, a10 = 0.f, a11 = 0.f;
#pragma unroll
    for (int ci = 0; ci < 16; ++ci) {
      const float4 w = *(const float4*)(wp + ci * 4);  // 64-lane broadcast
      a00 = fmaf(w.x, E[2 * ci + 0], a00);
      a01 = fmaf(w.y, E[2 * ci + 1], a01);
      a10 = fmaf(w.z, E[2 * ci + 0], a10);
      a11 = fmaf(w.w, E[2 * ci + 1], a11);
    }
    // out float4 #p = {o=2p,r0; o=2p,r1; o=2p+1,r0; o=2p+1,r1}
    op[4 * h + pp] = make_float4(__logf(a00), __logf(a01), __logf(a10), __logf(a11));
  }
}

extern "C" void kernel_launch(void* const* d_in, const int* in_sizes, int n_in,
                              void* d_out, int out_size, void* d_ws, size_t ws_size,
                              hipStream_t stream) {
  const float* ll     = (const float*)d_in[0];
  const float* logits = (const float*)d_in[1];
  float* out = (float*)d_out;
  // 131072 rows x 2 threads/row / 256 threads = 1024 blocks (one kk per block)
  sumconv_fused<<<1024, 256, 0, stream>>>(ll, logits, out);
}

// Round 6
// 13.513 us; speedup vs baseline: 1.1437x; 1.1437x over previous
//
#include <hip/hip_runtime.h>

// out[b,f,o,r] = log( sum_cin softmax(logits)[o,cin,ki,kj,r] * exp(ll[b,f,cin,r]) )
// ki=(f>>5)&3, kj=f&3. B=128, F=1024, CIN=16, COUT=16, K=4, R=2.
//
// v7 == v5 (session best, 13.61 us): 2 rows/thread (same f, adjacent b =>
// same kk slice; W float4 feeds 8 FMAs), weights from LDS per-ci, 35 KB LDS
// -> 4 blocks/CU (16 waves/CU), one barrier (lgkmcnt only; global loads stay
// in flight), 16 independent acc chains/thread. All LDS patterns broadcast
// or <=2-way (free, m136). At the memory roofline: 33.6 MB compulsory HBM
// traffic ~= 5.2 us @ 6.5 TB/s; measured dur includes ~8.5 us fixed
// dispatch overhead (verified by 6-structure A/B ledger, rounds 0-5).

#define WSTRIDE 520
#define ESTRIDE 36

#define EXP4(v) make_float4(__expf(v.x), __expf(v.y), __expf(v.z), __expf(v.w))

__global__ __launch_bounds__(256, 4) void sumconv_fused(
    const float* __restrict__ ll, const float* __restrict__ logits,
    float* __restrict__ out) {
  __shared__ float swW[8 * WSTRIDE];    // 16,640 B
  __shared__ float swE[128 * ESTRIDE];  // 18,432 B   (total 35,072 B)

  const int tid = threadIdx.x;
  const int blk = blockIdx.x;
  const int f0 = (blk & 15) * 64;   // f tile [f0, f0+64)
  const int b0 = (blk >> 4) * 2;    // 2 batch slabs
  const int kkbase = ((f0 >> 5) & 3) * 4;  // in {0, 8}

  // ---- issue both slabs' loads first (in flight during softmax) ----
  const float4* __restrict__ s0 = (const float4*)(ll + ((size_t)(b0 + 0) * 1024 + f0) * 32);
  const float4* __restrict__ s1 = (const float4*)(ll + ((size_t)(b0 + 1) * 1024 + f0) * 32);
  const float4 A0 = s0[tid], A1 = s0[tid + 256];
  const float4 B0 = s1[tid], B1 = s1[tid + 256];

  // ---- softmax of the 8 needed kk slices (exactly 1 task/thread) ----
  {
    const int r = tid & 1, kkloc = (tid >> 1) & 7, o = tid >> 4;
    const float* __restrict__ lg = logits + o * 512 + (kkbase + kkloc) * 2 + r;
    float v[16];
    float m = -1e30f;
#pragma unroll
    for (int ci = 0; ci < 16; ++ci) {
      v[ci] = lg[ci * 32];
      m = fmaxf(m, v[ci]);
    }
    float sum = 0.f;
#pragma unroll
    for (int ci = 0; ci < 16; ++ci) {
      v[ci] = __expf(v[ci] - m);
      sum += v[ci];
    }
    const float inv = 1.0f / sum;
#pragma unroll
    for (int ci = 0; ci < 16; ++ci)
      swW[kkloc * WSTRIDE + ci * 32 + o * 2 + r] = v[ci] * inv;
  }

  // ---- stage exp(ll): slab0 -> E-rows 0..63, slab1 -> E-rows 64..127 ----
  {
    const int row = tid >> 3, c4 = (tid & 7) * 4;
    *(float4*)(swE + (row +  0) * ESTRIDE + c4) = EXP4(A0);
    *(float4*)(swE + (row + 32) * ESTRIDE + c4) = EXP4(A1);
    *(float4*)(swE + (row + 64) * ESTRIDE + c4) = EXP4(B0);
    *(float4*)(swE + (row + 96) * ESTRIDE + c4) = EXP4(B1);
  }
  asm volatile("s_waitcnt lgkmcnt(0)" ::: "memory");
  __builtin_amdgcn_s_barrier();

  // ---- main: thread (row, q) -> o in {2q,2q+1,2q+8,2q+9}, rows (b0,f),(b0+1,f) ----
  const int row = tid >> 2, q = tid & 3;
  const int f = f0 + row;
  const int kk = (((f >> 5) & 3) << 2) | (f & 3);
  const float* __restrict__ wb = swW + (kk & 7) * WSTRIDE + q * 4;

  float Ef0[32], Ef1[32];
  {
    const float* __restrict__ e0 = swE + row * ESTRIDE;
    const float* __restrict__ e1 = swE + (64 + row) * ESTRIDE;
#pragma unroll
    for (int k = 0; k < 8; ++k) {
      *(float4*)(Ef0 + 4 * k) = *(const float4*)(e0 + 4 * k);
      *(float4*)(Ef1 + 4 * k) = *(const float4*)(e1 + 4 * k);
    }
  }

  float a[16];  // [oo(2)][slab(2)][4]
#pragma unroll
  for (int t = 0; t < 16; ++t) a[t] = 0.f;
#pragma unroll
  for (int ci = 0; ci < 16; ++ci) {
    const float4 w0 = *(const float4*)(wb + ci * 32);       // o-pair (2q, 2q+1)
    const float4 w1 = *(const float4*)(wb + ci * 32 + 16);  // o-pair (2q+8, 2q+9)
    const float e00 = Ef0[2 * ci], e01 = Ef0[2 * ci + 1];
    const float e10 = Ef1[2 * ci], e11 = Ef1[2 * ci + 1];
    a[0]  = fmaf(w0.x, e00, a[0]);   a[1]  = fmaf(w0.y, e01, a[1]);
    a[2]  = fmaf(w0.z, e00, a[2]);   a[3]  = fmaf(w0.w, e01, a[3]);
    a[4]  = fmaf(w0.x, e10, a[4]);   a[5]  = fmaf(w0.y, e11, a[5]);
    a[6]  = fmaf(w0.z, e10, a[6]);   a[7]  = fmaf(w0.w, e11, a[7]);
    a[8]  = fmaf(w1.x, e00, a[8]);   a[9]  = fmaf(w1.y, e01, a[9]);
    a[10] = fmaf(w1.z, e00, a[10]);  a[11] = fmaf(w1.w, e01, a[11]);
    a[12] = fmaf(w1.x, e10, a[12]);  a[13] = fmaf(w1.y, e11, a[13]);
    a[14] = fmaf(w1.z, e10, a[14]);  a[15] = fmaf(w1.w, e11, a[15]);
  }

  float4* __restrict__ op0 = (float4*)(out + ((size_t)(b0 + 0) * 1024 + f) * 32);
  float4* __restrict__ op1 = (float4*)(out + ((size_t)(b0 + 1) * 1024 + f) * 32);
  op0[q]     = make_float4(__logf(a[0]),  __logf(a[1]),  __logf(a[2]),  __logf(a[3]));
  op1[q]     = make_float4(__logf(a[4]),  __logf(a[5]),  __logf(a[6]),  __logf(a[7]));
  op0[q + 4] = make_float4(__logf(a[8]),  __logf(a[9]),  __logf(a[10]), __logf(a[11]));
  op1[q + 4] = make_float4(__logf(a[12]), __logf(a[13]), __logf(a[14]), __logf(a[15]));
}

extern "C" void kernel_launch(void* const* d_in, const int* in_sizes, int n_in,
                              void* d_out, int out_size, void* d_ws, size_t ws_size,
                              hipStream_t stream) {
  const float* ll     = (const float*)d_in[0];
  const float* logits = (const float*)d_in[1];
  float* out = (float*)d_out;
  // 131072 rows / 128 rows-per-block = 1024 blocks (64 f x 2 b per block)
  sumconv_fused<<<1024, 256, 0, stream>>>(ll, logits, out);
}